// Round 1
// baseline (372.324 us; speedup 1.0000x reference)
//
#include <hip/hip_runtime.h>

#define CAP    256     // max candidates kept per image (expected ~66, sigma ~8)
#define KDET   300
#define NWORDS 5       // ceil(KDET/64)

__global__ void zero_counts_kernel(int* counts, int n) {
    int i = blockIdx.x * blockDim.x + threadIdx.x;
    if (i < n) counts[i] = 0;
}

// One thread per (n, anchor, pixel); tid layout = (n*3 + a)*HW + pix so that
// consecutive lanes read consecutive pix -> coalesced conf-plane loads.
__global__ __launch_bounds__(256) void decode_kernel(
        const float* __restrict__ out,
        const float* __restrict__ anchors,   // [3][2]
        const float* __restrict__ thresh_p,
        int H, int W, float stride, int base, int total,
        float* __restrict__ cand, int* __restrict__ counts) {
    int tid = blockIdx.x * blockDim.x + threadIdx.x;
    if (tid >= total) return;
    int HW  = H * W;
    int pix = tid % HW;
    int na  = tid / HW;
    int a   = na % 3;
    int n   = na / 3;

    const float* p = out + ((size_t)(n * 255 + a * 85)) * HW + pix;
    float conf = p[0];
    if (!(conf > *thresh_p)) return;   // ~0.6% of lanes continue

    float o1 = p[(size_t)1 * HW];
    float o2 = p[(size_t)2 * HW];
    float o3 = p[(size_t)3 * HW];
    float o4 = p[(size_t)4 * HW];
    int gx = pix % W, gy = pix / W;
    float ox = ((float)gx + o1) * stride;
    float oy = ((float)gy + o2) * stride;
    float bw = expf(o3) * anchors[2 * a + 0];
    float bh = expf(o4) * anchors[2 * a + 1];

    // argmax over 80 classes, first-occurrence tie semantics (strict >)
    float best = p[(size_t)5 * HW];
    int cls = 0;
    for (int c = 1; c < 80; ++c) {
        float v = p[(size_t)(5 + c) * HW];
        if (v > best) { best = v; cls = c; }
    }

    int idx = base + pix * 3 + a;      // global concat-order box index
    int slot = atomicAdd(&counts[n], 1);
    if (slot < CAP) {
        float* r = cand + ((size_t)n * CAP + slot) * 8;
        r[0] = conf; r[1] = ox; r[2] = oy; r[3] = bw;
        r[4] = bh;   r[5] = (float)cls; r[6] = (float)idx; r[7] = 0.f;
    }
}

// One block per image: rank-sort candidates, build suppression bitmask, greedy NMS.
__global__ __launch_bounds__(256) void nms_kernel(
        const float* __restrict__ cand,
        const int* __restrict__ counts,
        float* __restrict__ out) {
    int n   = blockIdx.x;
    int tid = threadIdx.x;

    __shared__ float s_conf[CAP], s_cx[CAP], s_cy[CAP], s_w[CAP], s_h[CAP], s_cls[CAP], s_idx[CAP];
    __shared__ float r_conf[KDET], r_cx[KDET], r_cy[KDET], r_w[KDET], r_h[KDET], r_cls[KDET];
    __shared__ float s_x1[KDET], s_y1[KDET], s_x2[KDET], s_y2[KDET];
    __shared__ unsigned long long sup[KDET][NWORDS];
    __shared__ unsigned long long keepmask[NWORDS];

    int cnt = counts[n];
    if (cnt > CAP) cnt = CAP;
    int cnt_sel = cnt < KDET ? cnt : KDET;

    const float* cbase = cand + (size_t)n * CAP * 8;
    for (int i = tid; i < cnt; i += blockDim.x) {
        const float* r = cbase + (size_t)i * 8;
        s_conf[i] = r[0]; s_cx[i] = r[1]; s_cy[i] = r[2];
        s_w[i]    = r[3]; s_h[i]  = r[4]; s_cls[i] = r[5]; s_idx[i] = r[6];
    }
    __syncthreads();

    // rank = #{j : conf_j > conf_i || (conf_j == conf_i && idx_j < idx_i)}
    // matches jax.lax.top_k (descending, ties -> lower index first)
    for (int i = tid; i < cnt; i += blockDim.x) {
        float ci = s_conf[i], ii = s_idx[i];
        int rank = 0;
        for (int j = 0; j < cnt; ++j) {
            float cj = s_conf[j];
            rank += (cj > ci) || (cj == ci && s_idx[j] < ii);
        }
        if (rank < KDET) {
            float cx = s_cx[i], cy = s_cy[i], w = s_w[i], h = s_h[i];
            r_conf[rank] = ci; r_cx[rank] = cx; r_cy[rank] = cy;
            r_w[rank] = w;     r_h[rank] = h;   r_cls[rank] = s_cls[i];
            s_x1[rank] = cx - 0.5f * w;
            s_y1[rank] = cy - 0.5f * h;
            s_x2[rank] = cx + 0.5f * w;
            s_y2[rank] = cy + 0.5f * h;
        }
    }
    __syncthreads();

    // suppression bitmask: sup[i] bit j  <=>  iou(i,j) > 0.3 && same class
    int items = cnt_sel * NWORDS;
    for (int t = tid; t < items; t += blockDim.x) {
        int i  = t / NWORDS;
        int wi = t % NWORDS;
        float xi1 = s_x1[i], yi1 = s_y1[i], xi2 = s_x2[i], yi2 = s_y2[i];
        float cli = r_cls[i];
        float area_i = (xi2 - xi1) * (yi2 - yi1);
        unsigned long long m = 0;
        int jbase = wi * 64;
        for (int b = 0; b < 64; ++b) {
            int j = jbase + b;
            if (j >= cnt_sel) break;
            if (j == i) continue;
            float xl = fmaxf(xi1, s_x1[j]);
            float yt = fmaxf(yi1, s_y1[j]);
            float xr = fminf(xi2, s_x2[j]);
            float yb = fminf(yi2, s_y2[j]);
            float inter = fmaxf(xr - xl, 0.f) * fmaxf(yb - yt, 0.f);
            float area_j = (s_x2[j] - s_x1[j]) * (s_y2[j] - s_y1[j]);
            float uni = area_i + area_j - inter;
            float iou = inter / fmaxf(uni, 1e-9f);
            if (iou > 0.3f && cli == r_cls[j]) m |= (1ull << b);
        }
        sup[i][wi] = m;
    }
    __syncthreads();

    // greedy scan (sequential dependency) — bitmask ops, thread 0 only
    if (tid == 0) {
        unsigned long long km[NWORDS];
        for (int w = 0; w < NWORDS; ++w) km[w] = 0ull;
        for (int i = 0; i < cnt_sel; ++i) {
            unsigned long long s = 0;
            for (int w = 0; w < NWORDS; ++w) s |= sup[i][w] & km[w];
            if (s == 0) km[i >> 6] |= (1ull << (i & 63));
        }
        for (int w = 0; w < NWORDS; ++w) keepmask[w] = km[w];
    }
    __syncthreads();

    // write (KDET,7): zeros for suppressed / invalid rows
    float* obase = out + (size_t)n * KDET * 7;
    float nf = (float)n;
    for (int t = tid; t < KDET * 7; t += blockDim.x) {
        int r = t / 7, c = t % 7;
        float v = 0.f;
        if (r < cnt_sel && ((keepmask[r >> 6] >> (r & 63)) & 1ull)) {
            switch (c) {
                case 0: v = r_conf[r]; break;
                case 1: v = r_cx[r];   break;
                case 2: v = r_cy[r];   break;
                case 3: v = r_w[r];    break;
                case 4: v = r_h[r];    break;
                case 5: v = r_cls[r];  break;
                case 6: v = nf;        break;
            }
        }
        obase[t] = v;
    }
}

extern "C" void kernel_launch(void* const* d_in, const int* in_sizes, int n_in,
                              void* d_out, int out_size, void* d_ws, size_t ws_size,
                              hipStream_t stream) {
    const float* out13 = (const float*)d_in[0];
    const float* out26 = (const float*)d_in[1];
    const float* out52 = (const float*)d_in[2];
    const float* a13   = (const float*)d_in[3];
    const float* a26   = (const float*)d_in[4];
    const float* a52   = (const float*)d_in[5];
    const float* thr   = (const float*)d_in[6];
    float* out = (float*)d_out;

    int N = in_sizes[0] / (255 * 13 * 13);   // 64

    int*   counts = (int*)d_ws;
    float* cand   = (float*)((char*)d_ws + 256);   // N*CAP*8 floats = 512 KiB

    zero_counts_kernel<<<1, 64, 0, stream>>>(counts, N);

    int t13 = N * 3 * 13 * 13;
    int t26 = N * 3 * 26 * 26;
    int t52 = N * 3 * 52 * 52;
    decode_kernel<<<(t13 + 255) / 256, 256, 0, stream>>>(out13, a13, thr, 13, 13, 32.f, 0,    t13, cand, counts);
    decode_kernel<<<(t26 + 255) / 256, 256, 0, stream>>>(out26, a26, thr, 26, 26, 16.f, 507,  t26, cand, counts);
    decode_kernel<<<(t52 + 255) / 256, 256, 0, stream>>>(out52, a52, thr, 52, 52, 8.f,  2535, t52, cand, counts);

    nms_kernel<<<N, 256, 0, stream>>>(cand, counts, out);
}

// Round 2
// 320.370 us; speedup vs baseline: 1.1622x; 1.1622x over previous
//
#include <hip/hip_runtime.h>

#define CAP  256    // max candidates per image (expected ~66, ~10 sigma margin)
#define KDET 300
#define NW   4      // ceil(CAP/64) suppression-mask words

// One block per image. Phases:
//  1) scan conf planes (coalesced), LDS-append passing boxes
//  2) decode candidates (one lane per candidate, independent scattered loads)
//  3) rank-sort by (conf desc, idx asc)  == jax.lax.top_k tie semantics
//  4) build suppression bitmask (iou>0.3 && same class), greedy scan
//  5) write (KDET,7) rows, zeros for suppressed/invalid
__global__ __launch_bounds__(256) void yolo_fused_kernel(
        const float* __restrict__ o13, const float* __restrict__ o26,
        const float* __restrict__ o52,
        const float* __restrict__ a13, const float* __restrict__ a26,
        const float* __restrict__ a52,
        const float* __restrict__ thresh_p,
        float* __restrict__ out) {
    int n   = blockIdx.x;
    int tid = threadIdx.x;

    __shared__ int   l_cnt;
    __shared__ int   l_pack[CAP];            // s<<16 | a<<12 | pix
    __shared__ float l_conf[CAP];
    __shared__ float s_conf[CAP], s_cx[CAP], s_cy[CAP], s_w[CAP], s_h[CAP],
                     s_cls[CAP], s_idx[CAP];
    __shared__ float r_conf[CAP], r_cx[CAP], r_cy[CAP], r_w[CAP], r_h[CAP], r_cls[CAP];
    __shared__ float s_x1[CAP], s_y1[CAP], s_x2[CAP], s_y2[CAP];
    __shared__ unsigned long long sup[CAP][NW];
    __shared__ unsigned long long keepmask[NW];

    if (tid == 0) l_cnt = 0;
    __syncthreads();

    float thr = *thresh_p;

    // ---- phase 1: conf scan (uniform loop over scales, coalesced pix) ----
    for (int s = 0; s < 3; ++s) {
        const float* op = (s == 0) ? o13 : (s == 1) ? o26 : o52;
        int HW = (s == 0) ? 169 : (s == 1) ? 676 : 2704;
        for (int t = tid; t < 3 * HW; t += 256) {
            int a = t / HW, pix = t - a * HW;
            float conf = op[((size_t)(n * 255 + a * 85)) * HW + pix];
            if (conf > thr) {
                int slot = atomicAdd(&l_cnt, 1);
                if (slot < CAP) {
                    l_pack[slot] = (s << 16) | (a << 12) | pix;
                    l_conf[slot] = conf;
                }
            }
        }
    }
    __syncthreads();
    int cnt = l_cnt < CAP ? l_cnt : CAP;     // cnt <= 256 < KDET

    // ---- phase 2: decode candidates ----
    for (int i = tid; i < cnt; i += 256) {
        int pk  = l_pack[i];
        int s   = pk >> 16;
        int a   = (pk >> 12) & 0xF;
        int pix = pk & 0xFFF;
        const float* op = (s == 0) ? o13 : (s == 1) ? o26 : o52;
        const float* an = (s == 0) ? a13 : (s == 1) ? a26 : a52;
        int   HW     = (s == 0) ? 169 : (s == 1) ? 676 : 2704;
        int   W      = (s == 0) ? 13  : (s == 1) ? 26  : 52;
        float stride = (s == 0) ? 32.f : (s == 1) ? 16.f : 8.f;
        int   base   = (s == 0) ? 0   : (s == 1) ? 507 : 2535;

        const float* p = op + ((size_t)(n * 255 + a * 85)) * HW + pix;
        float o1 = p[(size_t)1 * HW];
        float o2 = p[(size_t)2 * HW];
        float o3 = p[(size_t)3 * HW];
        float o4 = p[(size_t)4 * HW];
        int gx = pix % W, gy = pix / W;
        float ox = ((float)gx + o1) * stride;
        float oy = ((float)gy + o2) * stride;
        float bw = expf(o3) * an[2 * a + 0];
        float bh = expf(o4) * an[2 * a + 1];

        float best = p[(size_t)5 * HW];      // argmax, strict > = first occurrence
        int cls = 0;
        for (int c = 1; c < 80; ++c) {
            float v = p[(size_t)(5 + c) * HW];
            if (v > best) { best = v; cls = c; }
        }

        s_conf[i] = l_conf[i];
        s_cx[i] = ox; s_cy[i] = oy; s_w[i] = bw; s_h[i] = bh;
        s_cls[i] = (float)cls;
        s_idx[i] = (float)(base + pix * 3 + a);
    }
    __syncthreads();

    // ---- phase 3: rank-sort (descending conf, ties -> lower concat idx) ----
    for (int i = tid; i < cnt; i += 256) {
        float ci = s_conf[i], ii = s_idx[i];
        int rank = 0;
        for (int j = 0; j < cnt; ++j) {
            float cj = s_conf[j];
            rank += (cj > ci) || (cj == ci && s_idx[j] < ii);
        }
        float cx = s_cx[i], cy = s_cy[i], w = s_w[i], h = s_h[i];
        r_conf[rank] = ci; r_cx[rank] = cx; r_cy[rank] = cy;
        r_w[rank] = w;     r_h[rank] = h;   r_cls[rank] = s_cls[i];
        s_x1[rank] = cx - 0.5f * w;
        s_y1[rank] = cy - 0.5f * h;
        s_x2[rank] = cx + 0.5f * w;
        s_y2[rank] = cy + 0.5f * h;
    }
    __syncthreads();

    // ---- phase 4a: suppression bitmask ----
    int nwords = (cnt + 63) >> 6;
    int items  = cnt * nwords;
    for (int t = tid; t < items; t += 256) {
        int i  = t / nwords;
        int wi = t - i * nwords;
        float xi1 = s_x1[i], yi1 = s_y1[i], xi2 = s_x2[i], yi2 = s_y2[i];
        float cli = r_cls[i];
        float area_i = (xi2 - xi1) * (yi2 - yi1);
        unsigned long long m = 0;
        int jbase = wi << 6;
        for (int b = 0; b < 64; ++b) {
            int j = jbase + b;
            if (j >= cnt) break;
            if (j == i) continue;
            float xl = fmaxf(xi1, s_x1[j]);
            float yt = fmaxf(yi1, s_y1[j]);
            float xr = fminf(xi2, s_x2[j]);
            float yb = fminf(yi2, s_y2[j]);
            float inter  = fmaxf(xr - xl, 0.f) * fmaxf(yb - yt, 0.f);
            float area_j = (s_x2[j] - s_x1[j]) * (s_y2[j] - s_y1[j]);
            float iou    = inter / fmaxf(area_i + area_j - inter, 1e-9f);
            if (iou > 0.3f && cli == r_cls[j]) m |= (1ull << b);
        }
        sup[i][wi] = m;
    }
    __syncthreads();

    // ---- phase 4b: greedy scan (sequential), thread 0 ----
    if (tid == 0) {
        unsigned long long km[NW];
        for (int w = 0; w < NW; ++w) km[w] = 0ull;
        for (int i = 0; i < cnt; ++i) {
            unsigned long long sbits = 0;
            for (int w = 0; w < nwords; ++w) sbits |= sup[i][w] & km[w];
            if (sbits == 0) km[i >> 6] |= (1ull << (i & 63));
        }
        for (int w = 0; w < NW; ++w) keepmask[w] = km[w];
    }
    __syncthreads();

    // ---- phase 5: write (KDET,7) ----
    float* obase = out + (size_t)n * KDET * 7;
    float nf = (float)n;
    for (int t = tid; t < KDET * 7; t += 256) {
        int r = t / 7, c = t - r * 7;
        float v = 0.f;
        if (r < cnt && ((keepmask[r >> 6] >> (r & 63)) & 1ull)) {
            switch (c) {
                case 0: v = r_conf[r]; break;
                case 1: v = r_cx[r];   break;
                case 2: v = r_cy[r];   break;
                case 3: v = r_w[r];    break;
                case 4: v = r_h[r];    break;
                case 5: v = r_cls[r];  break;
                case 6: v = nf;        break;
            }
        }
        obase[t] = v;
    }
}

extern "C" void kernel_launch(void* const* d_in, const int* in_sizes, int n_in,
                              void* d_out, int out_size, void* d_ws, size_t ws_size,
                              hipStream_t stream) {
    const float* out13 = (const float*)d_in[0];
    const float* out26 = (const float*)d_in[1];
    const float* out52 = (const float*)d_in[2];
    const float* a13   = (const float*)d_in[3];
    const float* a26   = (const float*)d_in[4];
    const float* a52   = (const float*)d_in[5];
    const float* thr   = (const float*)d_in[6];
    float* out = (float*)d_out;

    int N = in_sizes[0] / (255 * 13 * 13);   // 64

    yolo_fused_kernel<<<N, 256, 0, stream>>>(out13, out26, out52,
                                             a13, a26, a52, thr, out);
}

// Round 3
// 305.717 us; speedup vs baseline: 1.2179x; 1.0479x over previous
//
#include <hip/hip_runtime.h>

#define CAP  256    // max candidates per image (expected ~66, ~10 sigma margin)
#define KDET 300
#define NW   4      // ceil(CAP/64) suppression-mask words
#define BDIM 512

// One block per image. Phases:
//  1) scan conf planes (float4-vectorized, coalesced), LDS-append passing boxes
//  2) decode candidates (one lane per candidate, independent scattered loads)
//  3) rank-sort by (conf desc, idx asc)  == jax.lax.top_k tie semantics
//  4) build suppression bitmask (iou>0.3 && same class), greedy scan
//  5) write (KDET,7) rows, zeros for suppressed/invalid
__global__ __launch_bounds__(BDIM) void yolo_fused_kernel(
        const float* __restrict__ o13, const float* __restrict__ o26,
        const float* __restrict__ o52,
        const float* __restrict__ a13, const float* __restrict__ a26,
        const float* __restrict__ a52,
        const float* __restrict__ thresh_p,
        float* __restrict__ out) {
    int n   = blockIdx.x;
    int tid = threadIdx.x;

    __shared__ int   l_cnt;
    __shared__ int   l_pack[CAP];            // s<<16 | a<<12 | pix
    __shared__ float l_conf[CAP];
    __shared__ float s_conf[CAP], s_cx[CAP], s_cy[CAP], s_w[CAP], s_h[CAP],
                     s_cls[CAP], s_idx[CAP];
    __shared__ float r_conf[CAP], r_cx[CAP], r_cy[CAP], r_w[CAP], r_h[CAP], r_cls[CAP];
    __shared__ float s_x1[CAP], s_y1[CAP], s_x2[CAP], s_y2[CAP];
    __shared__ unsigned long long sup[CAP][NW];
    __shared__ unsigned long long keepmask[NW];

    if (tid == 0) l_cnt = 0;
    __syncthreads();

    float thr = *thresh_p;

    // ---- phase 1: conf scan ----
    // s=0 (13x13, HW=169, odd -> scalar): 3 planes x 169 = 507 loads
    for (int t = tid; t < 507; t += BDIM) {
        int a = t / 169, pix = t - a * 169;
        float conf = o13[((size_t)(n * 255 + a * 85)) * 169 + pix];
        if (conf > thr) {
            int slot = atomicAdd(&l_cnt, 1);
            if (slot < CAP) { l_pack[slot] = (0 << 16) | (a << 12) | pix; l_conf[slot] = conf; }
        }
    }
    // s=1 (26x26, HW=676): 3 planes x 169 float4
    for (int t = tid; t < 507; t += BDIM) {
        int a = t / 169, v = t - a * 169;
        const float4 c4 = *(const float4*)(o26 + ((size_t)(n * 255 + a * 85)) * 676 + v * 4);
        #pragma unroll
        for (int k = 0; k < 4; ++k) {
            float conf = (&c4.x)[k];
            if (conf > thr) {
                int slot = atomicAdd(&l_cnt, 1);
                if (slot < CAP) { l_pack[slot] = (1 << 16) | (a << 12) | (v * 4 + k); l_conf[slot] = conf; }
            }
        }
    }
    // s=2 (52x52, HW=2704): 3 planes x 676 float4
    for (int t = tid; t < 2028; t += BDIM) {
        int a = t / 676, v = t - a * 676;
        const float4 c4 = *(const float4*)(o52 + ((size_t)(n * 255 + a * 85)) * 2704 + v * 4);
        #pragma unroll
        for (int k = 0; k < 4; ++k) {
            float conf = (&c4.x)[k];
            if (conf > thr) {
                int slot = atomicAdd(&l_cnt, 1);
                if (slot < CAP) { l_pack[slot] = (2 << 16) | (a << 12) | (v * 4 + k); l_conf[slot] = conf; }
            }
        }
    }
    __syncthreads();
    int cnt = l_cnt < CAP ? l_cnt : CAP;     // cnt <= 256 < KDET

    // ---- phase 2: decode candidates ----
    for (int i = tid; i < cnt; i += BDIM) {
        int pk  = l_pack[i];
        int s   = pk >> 16;
        int a   = (pk >> 12) & 0xF;
        int pix = pk & 0xFFF;
        const float* op = (s == 0) ? o13 : (s == 1) ? o26 : o52;
        const float* an = (s == 0) ? a13 : (s == 1) ? a26 : a52;
        int   HW     = (s == 0) ? 169 : (s == 1) ? 676 : 2704;
        int   W      = (s == 0) ? 13  : (s == 1) ? 26  : 52;
        float stride = (s == 0) ? 32.f : (s == 1) ? 16.f : 8.f;
        int   base   = (s == 0) ? 0   : (s == 1) ? 507 : 2535;

        const float* p = op + ((size_t)(n * 255 + a * 85)) * HW + pix;
        float o1 = p[(size_t)1 * HW];
        float o2 = p[(size_t)2 * HW];
        float o3 = p[(size_t)3 * HW];
        float o4 = p[(size_t)4 * HW];
        int gx = pix % W, gy = pix / W;
        float ox = ((float)gx + o1) * stride;
        float oy = ((float)gy + o2) * stride;
        float bw = expf(o3) * an[2 * a + 0];
        float bh = expf(o4) * an[2 * a + 1];

        float best = p[(size_t)5 * HW];      // argmax, strict > = first occurrence
        int cls = 0;
        for (int c = 1; c < 80; ++c) {
            float v = p[(size_t)(5 + c) * HW];
            if (v > best) { best = v; cls = c; }
        }

        s_conf[i] = l_conf[i];
        s_cx[i] = ox; s_cy[i] = oy; s_w[i] = bw; s_h[i] = bh;
        s_cls[i] = (float)cls;
        s_idx[i] = (float)(base + pix * 3 + a);
    }
    __syncthreads();

    // ---- phase 3: rank-sort (descending conf, ties -> lower concat idx) ----
    for (int i = tid; i < cnt; i += BDIM) {
        float ci = s_conf[i], ii = s_idx[i];
        int rank = 0;
        for (int j = 0; j < cnt; ++j) {
            float cj = s_conf[j];
            rank += (cj > ci) || (cj == ci && s_idx[j] < ii);
        }
        float cx = s_cx[i], cy = s_cy[i], w = s_w[i], h = s_h[i];
        r_conf[rank] = ci; r_cx[rank] = cx; r_cy[rank] = cy;
        r_w[rank] = w;     r_h[rank] = h;   r_cls[rank] = s_cls[i];
        s_x1[rank] = cx - 0.5f * w;
        s_y1[rank] = cy - 0.5f * h;
        s_x2[rank] = cx + 0.5f * w;
        s_y2[rank] = cy + 0.5f * h;
    }
    __syncthreads();

    // ---- phase 4a: suppression bitmask ----
    int nwords = (cnt + 63) >> 6;
    int items  = cnt * nwords;
    for (int t = tid; t < items; t += BDIM) {
        int i  = t / nwords;
        int wi = t - i * nwords;
        float xi1 = s_x1[i], yi1 = s_y1[i], xi2 = s_x2[i], yi2 = s_y2[i];
        float cli = r_cls[i];
        float area_i = (xi2 - xi1) * (yi2 - yi1);
        unsigned long long m = 0;
        int jbase = wi << 6;
        for (int b = 0; b < 64; ++b) {
            int j = jbase + b;
            if (j >= cnt) break;
            if (j == i) continue;
            float xl = fmaxf(xi1, s_x1[j]);
            float yt = fmaxf(yi1, s_y1[j]);
            float xr = fminf(xi2, s_x2[j]);
            float yb = fminf(yi2, s_y2[j]);
            float inter  = fmaxf(xr - xl, 0.f) * fmaxf(yb - yt, 0.f);
            float area_j = (s_x2[j] - s_x1[j]) * (s_y2[j] - s_y1[j]);
            float iou    = inter / fmaxf(area_i + area_j - inter, 1e-9f);
            if (iou > 0.3f && cli == r_cls[j]) m |= (1ull << b);
        }
        sup[i][wi] = m;
    }
    __syncthreads();

    // ---- phase 4b: greedy scan (sequential), thread 0 ----
    if (tid == 0) {
        unsigned long long km[NW];
        for (int w = 0; w < NW; ++w) km[w] = 0ull;
        for (int i = 0; i < cnt; ++i) {
            unsigned long long sbits = 0;
            for (int w = 0; w < nwords; ++w) sbits |= sup[i][w] & km[w];
            if (sbits == 0) km[i >> 6] |= (1ull << (i & 63));
        }
        for (int w = 0; w < NW; ++w) keepmask[w] = km[w];
    }
    __syncthreads();

    // ---- phase 5: write (KDET,7) ----
    float* obase = out + (size_t)n * KDET * 7;
    float nf = (float)n;
    for (int t = tid; t < KDET * 7; t += BDIM) {
        int r = t / 7, c = t - r * 7;
        float v = 0.f;
        if (r < cnt && ((keepmask[r >> 6] >> (r & 63)) & 1ull)) {
            switch (c) {
                case 0: v = r_conf[r]; break;
                case 1: v = r_cx[r];   break;
                case 2: v = r_cy[r];   break;
                case 3: v = r_w[r];    break;
                case 4: v = r_h[r];    break;
                case 5: v = r_cls[r];  break;
                case 6: v = nf;        break;
            }
        }
        obase[t] = v;
    }
}

extern "C" void kernel_launch(void* const* d_in, const int* in_sizes, int n_in,
                              void* d_out, int out_size, void* d_ws, size_t ws_size,
                              hipStream_t stream) {
    const float* out13 = (const float*)d_in[0];
    const float* out26 = (const float*)d_in[1];
    const float* out52 = (const float*)d_in[2];
    const float* a13   = (const float*)d_in[3];
    const float* a26   = (const float*)d_in[4];
    const float* a52   = (const float*)d_in[5];
    const float* thr   = (const float*)d_in[6];
    float* out = (float*)d_out;

    int N = in_sizes[0] / (255 * 13 * 13);   // 64

    yolo_fused_kernel<<<N, BDIM, 0, stream>>>(out13, out26, out52,
                                              a13, a26, a52, thr, out);
}